// Round 2
// baseline (432.018 us; speedup 1.0000x reference)
//
#include <hip/hip_runtime.h>
#include <math.h>

#define NPTS 120000
#define NLID 100000
#define NRAD 20000
#define NTOT (2 * NPTS)
#define MAPW 512
#define MAPHW (512 * 512)
#define NTILES 8192
#define PGRID 768   // 3 blocks/CU exactly; persistent, grid-stride over tiles

typedef short sh8 __attribute__((ext_vector_type(8)));
typedef float f32x4 __attribute__((ext_vector_type(4)));
typedef unsigned short u16;
typedef unsigned int u32;

// feat tile: 48 groups of 4 channel-rows x 64 px, [4][64] f32 per group, +8 f32 pad.
// A0 = groups 0..23 (kk 0..2), A1 = groups 24..47 (kk 3..5). H aliases into A1.
#define GSTR 264                          // floats per group: 4*64 + 8 pad
#define H1S 72
#define H2S 40
#define H3S 24
#define HWAVE (16 * (H1S + H2S + H3S))    // 2176 shorts per wave (4352 B)

#define MEMFENCE() asm volatile("" ::: "memory")
#define BARRIER() do { MEMFENCE(); __builtin_amdgcn_s_barrier(); MEMFENCE(); } while (0)

__device__ __forceinline__ float gelu_f(float x) {
    return 0.5f * x * (1.0f + erff(x * 0.7071067811865476f));
}
__device__ __forceinline__ u16 f2bf(float f) {  // RNE
    unsigned int u = __float_as_uint(f);
    return (u16)((u + 0x7FFFu + ((u >> 16) & 1u)) >> 16);
}
__device__ __forceinline__ float bf2f(u16 h) {
    return __uint_as_float((unsigned int)h << 16);
}

// ---------------- weight prep (unchanged): fuse lin+l1, B-frag swizzle ----------------
__global__ void wprep_kernel(const float* __restrict__ w_lin, const float* __restrict__ b_lin,
                             const float* __restrict__ w1, const float* __restrict__ b1,
                             const float* __restrict__ w2, const float* __restrict__ w3,
                             u16* __restrict__ wfrag1, u16* __restrict__ wfrag2,
                             u16* __restrict__ wfrag3, float* __restrict__ b_eff) {
    int e = blockIdx.x * blockDim.x + threadIdx.x;
    if (e < 12288) {
        int fi = e >> 9, r = e & 511, lane = r >> 3, j = r & 7;
        int kk = fi >> 2, nt = fi & 3;
        int k = kk * 32 + (lane >> 4) * 8 + j;
        int n = nt * 16 + (lane & 15);
        float val;
        if (k < 128) {
            float s = 0.f;
            for (int jj = 0; jj < 64; jj++) s += w_lin[k * 64 + jj] * w1[jj * 64 + n];
            val = s;
        } else {
            val = w1[(k - 64) * 64 + n];
        }
        wfrag1[e] = f2bf(val);
    } else if (e < 12288 + 2048) {
        int e2 = e - 12288;
        int fi = e2 >> 9, lane = (e2 >> 3) & 63, j = e2 & 7;
        int kk = fi >> 1, nt = fi & 1;
        int k = kk * 32 + (lane >> 4) * 8 + j;
        int n = nt * 16 + (lane & 15);
        wfrag2[e2] = f2bf(w2[k * 32 + n]);
    } else if (e < 12288 + 2048 + 512) {
        int e3 = e - 12288 - 2048;
        int lane = e3 >> 3, j = e3 & 7;
        int k = (lane >> 4) * 8 + j;
        int n = lane & 15;
        wfrag3[e3] = f2bf(w3[k * 16 + n]);
    } else if (e < 12288 + 2048 + 512 + 64) {
        int n = e - 12288 - 2048 - 512;
        float s = b1[n];
        for (int jj = 0; jj < 64; jj++) s += b_lin[jj] * w1[jj * 64 + n];
        b_eff[n] = s;
    }
}

// Issue the 6 per-wave DMA loads for half h (0: groups 0..23, 1: groups 24..47) of tile nb.
__device__ __forceinline__ void issue_half(int h, int nb, int lane, int wv, float* smem,
                                           const float* __restrict__ p0,
                                           const float* __restrict__ p1,
                                           const float* __restrict__ fl) {
    const int b  = nb >> 12;
    const int r  = (nb & 4095) >> 3;
    const int c0 = (nb & 7) << 6;
    const size_t off = (size_t)b * ((size_t)64 * MAPHW)
                     + (size_t)r * MAPW + (size_t)c0
                     + (size_t)(lane >> 4) * MAPHW
                     + (size_t)((lane & 15) * 4);
    #pragma unroll
    for (int s = 0; s < 6; s++) {
        const int idx = h * 6 + s;        // 0..11 over (map m, quad u)
        const int m = idx >> 2;           // h0: m=0,0,0,0,1,1  h1: m=1,1,2,2,2,2
        const int u = idx & 3;            // h0: u=0,1,2,3,0,1  h1: u=2,3,0,1,2,3
        const int g = u * 4 + wv;
        const int G = __builtin_amdgcn_readfirstlane(m * 16 + g);
        const float* base = (m == 0) ? p0 : ((m == 1) ? p1 : fl);
        const float* gp = base + off + (size_t)(g * 4) * MAPHW;
        __builtin_amdgcn_global_load_lds(
            (const __attribute__((address_space(1))) u32*)gp,
            (__attribute__((address_space(3))) u32*)(&smem[G * GSTR]),
            16, 0, 0);
    }
}

// ---------------- dense main: persistent blocks, half-tile double-buffered DMA ----------------
__global__ __launch_bounds__(256) void fbseg_dense_kernel(
    const float* __restrict__ p0, const float* __restrict__ p1,
    const float* __restrict__ fl,
    const u16* __restrict__ wfrag1, const u16* __restrict__ wfrag2,
    const u16* __restrict__ wfrag3, const float* __restrict__ b_eff,
    const float* __restrict__ b2, const float* __restrict__ b3,
    const float* __restrict__ w4, const float* __restrict__ b4,
    float* __restrict__ score)
{
    __shared__ __align__(16) float smem[48 * GSTR];  // 50688 B -> 3 blocks/CU

    const int tid  = threadIdx.x;
    const int wv   = tid >> 6;
    const int lane = tid & 63;
    const int lr   = lane & 15;
    const int lq   = lane >> 4;
    const int m0w  = wv * 16;
    const int col  = m0w + lr;

    // per-wave H scratch aliases the A1 region (groups 24..47)
    u16* Hbase = (u16*)(smem + 24 * GSTR) + wv * HWAVE;
    u16* H1w = Hbase;
    u16* H2w = Hbase + 16 * H1S;
    u16* H3w = Hbase + 16 * H1S + 16 * H2S;

    // hoist small per-lane constants out of the tile loop
    const float beffr0 = b_eff[lr], beffr1 = b_eff[16 + lr],
                beffr2 = b_eff[32 + lr], beffr3 = b_eff[48 + lr];
    const float b2r0 = b2[lr], b2r1 = b2[16 + lr];
    const float b3r = b3[lr];
    const float b4r = b4[0];

    int nb = blockIdx.x;
    // prologue: fill both halves of the first tile (12 loads/wave in flight)
    issue_half(0, nb, lane, wv, smem, p0, p1, fl);
    issue_half(1, nb, lane, wv, smem, p0, p1, fl);

    while (true) {
        const int nbn = nb + PGRID;
        const bool more = (nbn < NTILES);

        // ---- A0 ready: 6 oldest (this tile's half-0) done; half-1 stays in flight ----
        asm volatile("s_waitcnt vmcnt(6)" ::: "memory");
        BARRIER();

        f32x4 acc1[4] = {};
        #pragma unroll
        for (int kk = 0; kk < 3; kk++) {
            sh8 a;
            u16* ap = (u16*)&a;
            #pragma unroll
            for (int j = 0; j < 8; j++) {
                const int k = kk * 32 + lq * 8 + j;
                ap[j] = f2bf(smem[(k >> 2) * GSTR + (k & 3) * 64 + col]);
            }
            #pragma unroll
            for (int nt = 0; nt < 4; nt++) {
                sh8 bfr = *(const sh8*)(wfrag1 + ((kk * 4 + nt) * 64 + lane) * 8);
                acc1[nt] = __builtin_amdgcn_mfma_f32_16x16x32_bf16(a, bfr, acc1[nt], 0, 0, 0);
            }
        }

        // ---- A0 consumed by all waves -> refill it for the next tile ----
        asm volatile("s_waitcnt lgkmcnt(0)" ::: "memory");
        BARRIER();
        if (more) {
            issue_half(0, nbn, lane, wv, smem, p0, p1, fl);
            asm volatile("s_waitcnt vmcnt(6)" ::: "memory");  // this tile's half-1 done
        } else {
            asm volatile("s_waitcnt vmcnt(0)" ::: "memory");
        }
        BARRIER();  // all waves' half-1 visible

        #pragma unroll
        for (int kk = 3; kk < 6; kk++) {
            sh8 a;
            u16* ap = (u16*)&a;
            #pragma unroll
            for (int j = 0; j < 8; j++) {
                const int k = kk * 32 + lq * 8 + j;
                ap[j] = f2bf(smem[(k >> 2) * GSTR + (k & 3) * 64 + col]);
            }
            #pragma unroll
            for (int nt = 0; nt < 4; nt++) {
                sh8 bfr = *(const sh8*)(wfrag1 + ((kk * 4 + nt) * 64 + lane) * 8);
                acc1[nt] = __builtin_amdgcn_mfma_f32_16x16x32_bf16(a, bfr, acc1[nt], 0, 0, 0);
            }
        }

        // ---- A1 consumed by all waves -> safe to alias H into it ----
        asm volatile("s_waitcnt lgkmcnt(0)" ::: "memory");
        BARRIER();

        {
            const float bias[4] = {beffr0, beffr1, beffr2, beffr3};
            #pragma unroll
            for (int nt = 0; nt < 4; nt++) {
                const int n = nt * 16 + lr;
                #pragma unroll
                for (int rg = 0; rg < 4; rg++) {
                    const int row = lq * 4 + rg;
                    H1w[row * H1S + n] = f2bf(gelu_f(acc1[nt][rg] + bias[nt]));
                }
            }
        }

        // layer 2: K=64 -> N=32
        f32x4 acc2[2] = {};
        #pragma unroll
        for (int kk = 0; kk < 2; kk++) {
            sh8 a = *(const sh8*)&H1w[lr * H1S + kk * 32 + lq * 8];
            #pragma unroll
            for (int nt = 0; nt < 2; nt++) {
                sh8 bfr = *(const sh8*)(wfrag2 + ((kk * 2 + nt) * 64 + lane) * 8);
                acc2[nt] = __builtin_amdgcn_mfma_f32_16x16x32_bf16(a, bfr, acc2[nt], 0, 0, 0);
            }
        }
        {
            const float bias[2] = {b2r0, b2r1};
            #pragma unroll
            for (int nt = 0; nt < 2; nt++) {
                const int n = nt * 16 + lr;
                #pragma unroll
                for (int rg = 0; rg < 4; rg++) {
                    const int row = lq * 4 + rg;
                    H2w[row * H2S + n] = f2bf(gelu_f(acc2[nt][rg] + bias[nt]));
                }
            }
        }

        // layer 3: K=32 -> N=16
        f32x4 acc3 = {};
        {
            sh8 a = *(const sh8*)&H2w[lr * H2S + lq * 8];
            sh8 bfr = *(const sh8*)(wfrag3 + lane * 8);
            acc3 = __builtin_amdgcn_mfma_f32_16x16x32_bf16(a, bfr, acc3, 0, 0, 0);
        }
        #pragma unroll
        for (int rg = 0; rg < 4; rg++) {
            const int row = lq * 4 + rg;
            H3w[row * H3S + lr] = f2bf(gelu_f(acc3[rg] + b3r));
        }

        // layer 4 + sigmoid: lanes 0..15 finish one pixel each
        if (lane < 16) {
            float s = b4r;
            #pragma unroll
            for (int k = 0; k < 16; k++) s = fmaf(bf2f(H3w[lane * H3S + k]), w4[k], s);
            const int b  = nb >> 12;
            const int r  = (nb & 4095) >> 3;
            const int c0 = (nb & 7) << 6;
            score[(size_t)b * MAPHW + (size_t)r * MAPW + (size_t)(c0 + m0w + lane)] =
                1.0f / (1.0f + expf(-s));
        }

        // ---- H consumed by all waves -> A1 region free for next tile's DMA ----
        asm volatile("s_waitcnt lgkmcnt(0)" ::: "memory");
        BARRIER();
        if (!more) break;
        issue_half(1, nbn, lane, wv, smem, p0, p1, fl);
        nb = nbn;
    }
}

// ---------------- per-point resolve: score map is 2 MB -> L2-resident ----------------
__global__ void lookup_kernel(const int* __restrict__ lidar, const int* __restrict__ radar,
                              const float* __restrict__ score, float* __restrict__ out) {
    int p = blockIdx.x * blockDim.x + threadIdx.x;
    if (p >= NTOT) return;
    int b = p / NPTS;
    int i = p - b * NPTS;
    int r, c;
    if (i < NLID) {
        const int* cd = lidar + (size_t)(b * NLID + i) * 3;
        r = cd[1]; c = cd[2];
    } else {
        const int* cd = radar + (size_t)(b * NRAD + (i - NLID)) * 3;
        r = cd[1]; c = cd[2];
    }
    out[p] = score[(size_t)b * MAPHW + (size_t)r * MAPW + (size_t)c];
}

extern "C" void kernel_launch(void* const* d_in, const int* in_sizes, int n_in,
                              void* d_out, int out_size, void* d_ws, size_t ws_size,
                              hipStream_t stream) {
    const float* p0    = (const float*)d_in[0];
    const float* p1    = (const float*)d_in[1];
    const float* fl    = (const float*)d_in[2];
    const int*   lidar = (const int*)d_in[3];
    const int*   radar = (const int*)d_in[4];
    const float* w_lin = (const float*)d_in[5];
    const float* b_lin = (const float*)d_in[6];
    const float* w1    = (const float*)d_in[7];
    const float* b1    = (const float*)d_in[8];
    const float* w2    = (const float*)d_in[9];
    const float* b2    = (const float*)d_in[10];
    const float* w3    = (const float*)d_in[11];
    const float* b3    = (const float*)d_in[12];
    const float* w4    = (const float*)d_in[13];
    const float* b4    = (const float*)d_in[14];
    float* out = (float*)d_out;

    // ws layout: score_map (2 MB) | wfrag1 | wfrag2 | wfrag3 | b_eff
    char* ws = (char*)d_ws;
    float* score = (float*)ws;
    char* wbase  = ws + (size_t)2 * MAPHW * sizeof(float);
    u16*  wfrag1 = (u16*)wbase;
    u16*  wfrag2 = (u16*)(wbase + 12288 * 2);
    u16*  wfrag3 = (u16*)(wbase + (12288 + 2048) * 2);
    float* b_eff = (float*)(wbase + (12288 + 2048 + 512) * 2);

    hipLaunchKernelGGL(wprep_kernel, dim3((14912 + 255) / 256), dim3(256), 0, stream,
                       w_lin, b_lin, w1, b1, w2, w3, wfrag1, wfrag2, wfrag3, b_eff);
    hipLaunchKernelGGL(fbseg_dense_kernel, dim3(PGRID), dim3(256), 0, stream,
                       p0, p1, fl, wfrag1, wfrag2, wfrag3, b_eff, b2, b3, w4, b4, score);
    hipLaunchKernelGGL(lookup_kernel, dim3((NTOT + 255) / 256), dim3(256), 0, stream,
                       lidar, radar, score, out);
}

// Round 3
// 397.219 us; speedup vs baseline: 1.0876x; 1.0876x over previous
//
#include <hip/hip_runtime.h>
#include <math.h>

#define NPTS 120000
#define NLID 100000
#define NRAD 20000
#define NTOT (2 * NPTS)
#define MAPW 512
#define MAPHW (512 * 512)
#define NTILES 8192

typedef short sh8 __attribute__((ext_vector_type(8)));
typedef float f32x4 __attribute__((ext_vector_type(4)));
typedef unsigned short u16;
typedef unsigned int u32;

// bf16 feature tile: feat[192 ch][64 px], row stride CSTR u16.
// CSTR=70 (140 B, 35 dwords, odd) -> staging b32-pair writes and A-build u16
// reads are both bank-conflict-free (<=2 lanes/bank vs size-implied floor).
#define CSTR 70
#define H1S 72                            // H strides unchanged from verified kernel
#define H2S 40
#define H3S 24
#define HWAVE (16 * (H1S + H2S + H3S))    // 2176 u16 per wave

__device__ __forceinline__ float gelu_f(float x) {
    return 0.5f * x * (1.0f + erff(x * 0.7071067811865476f));
}
__device__ __forceinline__ u16 f2bf(float f) {  // RNE
    unsigned int u = __float_as_uint(f);
    return (u16)((u + 0x7FFFu + ((u >> 16) & 1u)) >> 16);
}
__device__ __forceinline__ float bf2f(u16 h) {
    return __uint_as_float((unsigned int)h << 16);
}

// ---------------- weight prep (unchanged): fuse lin+l1, B-frag swizzle ----------------
__global__ void wprep_kernel(const float* __restrict__ w_lin, const float* __restrict__ b_lin,
                             const float* __restrict__ w1, const float* __restrict__ b1,
                             const float* __restrict__ w2, const float* __restrict__ w3,
                             u16* __restrict__ wfrag1, u16* __restrict__ wfrag2,
                             u16* __restrict__ wfrag3, float* __restrict__ b_eff) {
    int e = blockIdx.x * blockDim.x + threadIdx.x;
    if (e < 12288) {
        int fi = e >> 9, r = e & 511, lane = r >> 3, j = r & 7;
        int kk = fi >> 2, nt = fi & 3;
        int k = kk * 32 + (lane >> 4) * 8 + j;
        int n = nt * 16 + (lane & 15);
        float val;
        if (k < 128) {
            float s = 0.f;
            for (int jj = 0; jj < 64; jj++) s += w_lin[k * 64 + jj] * w1[jj * 64 + n];
            val = s;
        } else {
            val = w1[(k - 64) * 64 + n];
        }
        wfrag1[e] = f2bf(val);
    } else if (e < 12288 + 2048) {
        int e2 = e - 12288;
        int fi = e2 >> 9, lane = (e2 >> 3) & 63, j = e2 & 7;
        int kk = fi >> 1, nt = fi & 1;
        int k = kk * 32 + (lane >> 4) * 8 + j;
        int n = nt * 16 + (lane & 15);
        wfrag2[e2] = f2bf(w2[k * 32 + n]);
    } else if (e < 12288 + 2048 + 512) {
        int e3 = e - 12288 - 2048;
        int lane = e3 >> 3, j = e3 & 7;
        int k = (lane >> 4) * 8 + j;
        int n = lane & 15;
        wfrag3[e3] = f2bf(w3[k * 16 + n]);
    } else if (e < 12288 + 2048 + 512 + 64) {
        int n = e - 12288 - 2048 - 512;
        float s = b1[n];
        for (int jj = 0; jj < 64; jj++) s += b_lin[jj] * w1[jj * 64 + n];
        b_eff[n] = s;
    }
}

// ---------------- dense main: reg-staged bf16 tile (26880 B -> 6 blocks/CU) ----------------
// grid: 8192 blocks; block nb -> b = nb>>12, r = (nb&4095)>>3, c0 = (nb&7)<<6.
__global__ __launch_bounds__(256, 6) void fbseg_dense_kernel(
    const float* __restrict__ p0, const float* __restrict__ p1,
    const float* __restrict__ fl,
    const u16* __restrict__ wfrag1, const u16* __restrict__ wfrag2,
    const u16* __restrict__ wfrag3, const float* __restrict__ b_eff,
    const float* __restrict__ b2, const float* __restrict__ b3,
    const float* __restrict__ w4, const float* __restrict__ b4,
    float* __restrict__ score)
{
    __shared__ __align__(16) u16 feat[192 * CSTR];  // 26880 B

    const int tid  = threadIdx.x;
    const int wv   = tid >> 6;
    const int lane = tid & 63;
    const int lr   = lane & 15;
    const int lq   = lane >> 4;
    const int m0w  = wv * 16;
    const int col  = m0w + lr;

    const int nb = blockIdx.x;
    const int b  = nb >> 12;
    const int r  = (nb & 4095) >> 3;
    const int c0 = (nb & 7) << 6;

    // ---- staging: wave wv loads channels [48wv, 48wv+48), converts, writes bf16 ----
    // lane: channel quad-member q = lane>>4, pixels p4..p4+3 = (lane&15)*4..
    {
        const int q  = lq;
        const int p4 = lr * 4;
        const size_t goff = (size_t)b * ((size_t)64 * MAPHW)
                          + (size_t)r * MAPW + (size_t)(c0 + p4);
        #pragma unroll
        for (int s = 0; s < 12; s++) {
            const int C4 = wv * 48 + s * 4;          // quad base channel (wave-uniform)
            const int C  = C4 + q;                   // this lane's channel (0..191)
            const float* mp = (C4 < 64) ? p0 : ((C4 < 128) ? p1 : fl);
            const f32x4 v = *(const f32x4*)(mp + goff + (size_t)(C & 63) * MAPHW);
            const u32 lo = ((u32)f2bf(v[1]) << 16) | (u32)f2bf(v[0]);
            const u32 hi = ((u32)f2bf(v[3]) << 16) | (u32)f2bf(v[2]);
            u32* dst = (u32*)(feat + C * CSTR + p4);  // dword-aligned (CSTR even*... p4 even)
            dst[0] = lo;
            dst[1] = hi;
        }
    }
    __syncthreads();

    // ---- layer 1: K=192 -> N=64 ; A read directly as bf16 (no convert) ----
    f32x4 acc1[4] = {};
    #pragma unroll
    for (int kk = 0; kk < 6; kk++) {
        sh8 a;
        u16* ap = (u16*)&a;
        #pragma unroll
        for (int j = 0; j < 8; j++)
            ap[j] = feat[(kk * 32 + lq * 8 + j) * CSTR + col];
        #pragma unroll
        for (int nt = 0; nt < 4; nt++) {
            sh8 bfr = *(const sh8*)(wfrag1 + ((kk * 4 + nt) * 64 + lane) * 8);
            acc1[nt] = __builtin_amdgcn_mfma_f32_16x16x32_bf16(a, bfr, acc1[nt], 0, 0, 0);
        }
    }
    __syncthreads();  // feat dead for ALL waves; reuse as per-wave H scratch

    u16* Hbase = feat + wv * HWAVE;
    u16* H1w = Hbase;
    u16* H2w = Hbase + 16 * H1S;
    u16* H3w = Hbase + 16 * H1S + 16 * H2S;

    #pragma unroll
    for (int nt = 0; nt < 4; nt++) {
        const int n = nt * 16 + lr;
        const float bias = b_eff[n];
        #pragma unroll
        for (int rg = 0; rg < 4; rg++) {
            const int row = lq * 4 + rg;
            H1w[row * H1S + n] = f2bf(gelu_f(acc1[nt][rg] + bias));
        }
    }

    // layer 2: K=64 -> N=32
    f32x4 acc2[2] = {};
    #pragma unroll
    for (int kk = 0; kk < 2; kk++) {
        sh8 a = *(const sh8*)&H1w[lr * H1S + kk * 32 + lq * 8];
        #pragma unroll
        for (int nt = 0; nt < 2; nt++) {
            sh8 bfr = *(const sh8*)(wfrag2 + ((kk * 2 + nt) * 64 + lane) * 8);
            acc2[nt] = __builtin_amdgcn_mfma_f32_16x16x32_bf16(a, bfr, acc2[nt], 0, 0, 0);
        }
    }
    #pragma unroll
    for (int nt = 0; nt < 2; nt++) {
        const int n = nt * 16 + lr;
        const float bias = b2[n];
        #pragma unroll
        for (int rg = 0; rg < 4; rg++) {
            const int row = lq * 4 + rg;
            H2w[row * H2S + n] = f2bf(gelu_f(acc2[nt][rg] + bias));
        }
    }

    // layer 3: K=32 -> N=16
    f32x4 acc3 = {};
    {
        sh8 a = *(const sh8*)&H2w[lr * H2S + lq * 8];
        sh8 bfr = *(const sh8*)(wfrag3 + lane * 8);
        acc3 = __builtin_amdgcn_mfma_f32_16x16x32_bf16(a, bfr, acc3, 0, 0, 0);
    }
    {
        const float bias = b3[lr];
        #pragma unroll
        for (int rg = 0; rg < 4; rg++) {
            const int row = lq * 4 + rg;
            H3w[row * H3S + lr] = f2bf(gelu_f(acc3[rg] + bias));
        }
    }

    // layer 4 + sigmoid: lanes 0..15 finish one pixel each, write score map
    if (lane < 16) {
        float s = b4[0];
        #pragma unroll
        for (int k = 0; k < 16; k++) s = fmaf(bf2f(H3w[lane * H3S + k]), w4[k], s);
        score[(size_t)b * MAPHW + (size_t)r * MAPW + (size_t)(c0 + m0w + lane)] =
            1.0f / (1.0f + expf(-s));
    }
}

// ---------------- per-point resolve: score map is 2 MB -> L2-resident ----------------
__global__ void lookup_kernel(const int* __restrict__ lidar, const int* __restrict__ radar,
                              const float* __restrict__ score, float* __restrict__ out) {
    int p = blockIdx.x * blockDim.x + threadIdx.x;
    if (p >= NTOT) return;
    int b = p / NPTS;
    int i = p - b * NPTS;
    int r, c;
    if (i < NLID) {
        const int* cd = lidar + (size_t)(b * NLID + i) * 3;
        r = cd[1]; c = cd[2];
    } else {
        const int* cd = radar + (size_t)(b * NRAD + (i - NLID)) * 3;
        r = cd[1]; c = cd[2];
    }
    out[p] = score[(size_t)b * MAPHW + (size_t)r * MAPW + (size_t)c];
}

extern "C" void kernel_launch(void* const* d_in, const int* in_sizes, int n_in,
                              void* d_out, int out_size, void* d_ws, size_t ws_size,
                              hipStream_t stream) {
    const float* p0    = (const float*)d_in[0];
    const float* p1    = (const float*)d_in[1];
    const float* fl    = (const float*)d_in[2];
    const int*   lidar = (const int*)d_in[3];
    const int*   radar = (const int*)d_in[4];
    const float* w_lin = (const float*)d_in[5];
    const float* b_lin = (const float*)d_in[6];
    const float* w1    = (const float*)d_in[7];
    const float* b1    = (const float*)d_in[8];
    const float* w2    = (const float*)d_in[9];
    const float* b2    = (const float*)d_in[10];
    const float* w3    = (const float*)d_in[11];
    const float* b3    = (const float*)d_in[12];
    const float* w4    = (const float*)d_in[13];
    const float* b4    = (const float*)d_in[14];
    float* out = (float*)d_out;

    // ws layout: score_map (2 MB) | wfrag1 | wfrag2 | wfrag3 | b_eff
    char* ws = (char*)d_ws;
    float* score = (float*)ws;
    char* wbase  = ws + (size_t)2 * MAPHW * sizeof(float);
    u16*  wfrag1 = (u16*)wbase;
    u16*  wfrag2 = (u16*)(wbase + 12288 * 2);
    u16*  wfrag3 = (u16*)(wbase + (12288 + 2048) * 2);
    float* b_eff = (float*)(wbase + (12288 + 2048 + 512) * 2);

    hipLaunchKernelGGL(wprep_kernel, dim3((14912 + 255) / 256), dim3(256), 0, stream,
                       w_lin, b_lin, w1, b1, w2, w3, wfrag1, wfrag2, wfrag3, b_eff);
    hipLaunchKernelGGL(fbseg_dense_kernel, dim3(NTILES), dim3(256), 0, stream,
                       p0, p1, fl, wfrag1, wfrag2, wfrag3, b_eff, b2, b3, w4, b4, score);
    hipLaunchKernelGGL(lookup_kernel, dim3((NTOT + 255) / 256), dim3(256), 0, stream,
                       lidar, radar, score, out);
}